// Round 8
// baseline (90.143 us; speedup 1.0000x reference)
//
#include <hip/hip_runtime.h>

#define HH 512
#define WW 512
#define RR 5
#define KS 11
#define EPS_F 1e-5f
#define NLOG2E 1.44269504088896340736f
#define TW 64                 // output tile width
#define TH 4                  // output tile height
#define BY 5                  // blockDim.y: 320 threads = 5 waves (strip fits in one pass)
#define SW (TW + 2 * RR)      // 74: strip width (x-halo)
#define SH (TH + 2 * RR)      // 14: t-tile height (y-halo)
#define NSTRIP (SW * TH)      // 296 strip pixels <= 320 threads

// R8 = R7 separable kernel with two fixes:
//  (1) 320 threads: pass V runs in ONE pass (R7: 296 px / 256 thr -> wave 0
//      ran the ~500-VALU body twice while others idled at the barrier).
//  (2) float4-interleaved class planes: (ch0,ch1,ch2,w) per exponent class ->
//      6 ds_write_b128 + 11 ds_read_b128 per px instead of 68 scalar b32 ops.
//      Consecutive-lane stride-16B = conflict-free b128 pattern.
// Algorithm (R7): k(i,j) = t_n^{i^2} * t_n^{j^2}, masked t=0 kills OOB taps.
//   Pass V: C_a(y,x) = sum_i img(y+i,x) * t(y+i,x)^(i^2+a), a in {0,1,4,9,16,25}
//   Pass H: out(y,x)  = sum_j C_{j^2}(y,x+j) / sum_j W_{j^2}(y,x+j)
// Codegen rules (R1-R6): scalar constexpr-indexed accumulators, straight-line
// unrolls, no guarded multi-output inner loops (those spilled to VGPR=256).
__global__ __launch_bounds__(320) void gauss_psf_kernel(const float* __restrict__ image,
                                                        const float* __restrict__ psf,
                                                        float* __restrict__ out) {
    __shared__ float4 cp[6 * NSTRIP];   // class planes, 28.4 KB
    __shared__ float  tt[SH * SW];      // masked t tile,  4.1 KB

    const int tx  = threadIdx.x;            // 0..63
    const int ty  = threadIdx.y;            // 0..4
    const int tid = ty * 64 + tx;           // 0..319
    const int bx0 = blockIdx.x * TW;
    const int by0 = blockIdx.y * TH;
    const int b   = blockIdx.z;

    const float* pw   = psf + (size_t)b * HH * WW;
    const float* img0 = image + (size_t)b * 3 * HH * WW;
    const float* img1 = img0 + HH * WW;
    const float* img2 = img0 + 2 * HH * WW;

    // ---- Phase 1: masked-t tile (14 x 74 = 1036 values, 4 passes of 320) ----
#pragma unroll
    for (int base = 0; base < SH * SW; base += 320) {
        const int idx = base + tid;
        if (idx < SH * SW) {
            const int row = idx / SW, col = idx - row * SW;
            const int gy = by0 - RR + row, gx = bx0 - RR + col;
            const bool in = ((unsigned)gy < (unsigned)HH) && ((unsigned)gx < (unsigned)WW);
            const int cy = gy < 0 ? 0 : (gy > HH - 1 ? HH - 1 : gy);
            const int cx = gx < 0 ? 0 : (gx > WW - 1 ? WW - 1 : gx);
            const float w = pw[cy * WW + cx];
            const float a = -NLOG2E * __builtin_amdgcn_rcpf(fmaf(2.0f * w, w, EPS_F));
            tt[idx] = in ? __builtin_amdgcn_exp2f(a) : 0.0f;
        }
    }
    __syncthreads();

    // ---- Pass V: 296 strip pixels, one per thread (tid < 296) ----
    if (tid < NSTRIP) {
        const int ly = tid / SW;            // 0..3
        const int lx = tid - ly * SW;       // 0..73
        const int gx = bx0 - RR + lx;
        const int gxc = gx < 0 ? 0 : (gx > WW - 1 ? WW - 1 : gx);
        const int gy = by0 + ly;

        float accw[6], acc0[6], acc1[6], acc2[6];
#pragma unroll
        for (int ai = 0; ai < 6; ++ai) { accw[ai] = acc0[ai] = acc1[ai] = acc2[ai] = 0.0f; }

#pragma unroll
        for (int r = 0; r < KS; ++r) {
            const float t = tt[(ly + r) * SW + lx];            // b32, const offset
            int ry = gy + r - RR;
            ry = ry < 0 ? 0 : (ry > HH - 1 ? HH - 1 : ry);
            const int ni = ry * WW + gxc;
            const float i0 = img0[ni];
            const float i1 = img1[ni];
            const float i2 = img2[ni];

            const float T2 = t * t, T4 = T2 * T2, T8 = T4 * T4, T16 = T8 * T8;
            const float P1 = t, P4 = T4, P9 = T8 * t, P16 = T16, P25 = T16 * P9;
            const float PA[6] = {1.0f, P1, P4, P9, P16, P25};  // constexpr-indexed
            const int ii = (r - RR) * (r - RR);                // constexpr after unroll
            const float u = ii == 0 ? 1.0f : ii == 1 ? P1 : ii == 4 ? P4
                          : ii == 9 ? P9 : ii == 16 ? P16 : P25;   // t^(i^2)

#pragma unroll
            for (int ai = 0; ai < 6; ++ai) {                   // constant trip, no guard
                const float f = u * PA[ai];                    // t^(i^2+a)
                accw[ai] += f;
                acc0[ai] = fmaf(i0, f, acc0[ai]);
                acc1[ai] = fmaf(i1, f, acc1[ai]);
                acc2[ai] = fmaf(i2, f, acc2[ai]);
            }
        }
#pragma unroll
        for (int ai = 0; ai < 6; ++ai)                         // 6 x ds_write_b128
            cp[ai * NSTRIP + tid] = make_float4(acc0[ai], acc1[ai], acc2[ai], accw[ai]);
    }
    __syncthreads();

    // ---- Pass H: 256 output pixels (waves 0-3); wave 4 exits uniformly ----
    if (tid < TW * TH) {
        const int hx = tid & 63, hy = tid >> 6;
        const int hb = hy * SW + hx;        // strip index of (y, x-RR+j) at j=0
        float s0 = 0.0f, s1 = 0.0f, s2 = 0.0f, sw = 0.0f;
#pragma unroll
        for (int j = 0; j < KS; ++j) {
            const int jj = (j - RR) * (j - RR);                // constexpr
            const int ai = jj == 0 ? 0 : jj == 1 ? 1 : jj == 4 ? 2
                         : jj == 9 ? 3 : jj == 16 ? 4 : 5;
            const float4 v = cp[ai * NSTRIP + hb + j];         // ds_read_b128
            s0 += v.x; s1 += v.y; s2 += v.z; sw += v.w;
        }

        float inv = __builtin_amdgcn_rcpf(sw);                 // sw >= 1 (center tap)
        inv = inv * (2.0f - sw * inv);                         // Newton: ~1e-7 rel
        const int x = bx0 + hx, y = by0 + hy;
        const int oi = y * WW + x;
        float* outb = out + (size_t)b * 3 * HH * WW;
        outb[oi]               = s0 * inv;
        outb[HH * WW + oi]     = s1 * inv;
        outb[2 * HH * WW + oi] = s2 * inv;
    }
}

extern "C" void kernel_launch(void* const* d_in, const int* in_sizes, int n_in,
                              void* d_out, int out_size, void* d_ws, size_t ws_size,
                              hipStream_t stream) {
    const float* image = (const float*)d_in[0];
    const float* psf   = (const float*)d_in[1];
    float* out = (float*)d_out;

    dim3 block(TW, BY, 1);                 // 320 threads = 5 waves
    dim3 grid(WW / TW, HH / TH, 4);        // 8 x 128 x 4 = 4096 blocks
    gauss_psf_kernel<<<grid, block, 0, stream>>>(image, psf, out);
}

// Round 9
// 85.467 us; speedup vs baseline: 1.0547x; 1.0547x over previous
//
#include <hip/hip_runtime.h>

#define HH 512
#define WW 512
#define RR 5
#define KS 11
#define EPS_F 1e-5f
#define NLOG2E 1.44269504088896340736f
#define TW 64                 // output tile width
#define TH 4                  // output tile height
#define BY 5                  // 320 threads = 5 waves; pass V in one pass
#define SW (TW + 2 * RR)      // 74: strip width (x-halo)
#define SH (TH + 2 * RR)      // 14: t-tile height (y-halo)
#define NSTRIP (SW * TH)      // 296 strip pixels <= 320 threads

typedef float f2 __attribute__((ext_vector_type(2)));
__device__ __forceinline__ f2 fma2(f2 a, f2 b, f2 c) { return __builtin_elementwise_fma(a, b, c); }

// R9 = R8 with packed-FP32 accumulation (v_pk_fma_f32 / v_pk_mul_f32 /
// v_pk_add_f32 on gfx950): classes packed in float2 pairs, channels broadcast.
// Per pass-V row: 3 pk_mul (class weights) + 9 pk_fma + 3 pk_add (accum)
// instead of ~11 mul + 6 add + 18 fma. R5-calibrated model says pass-V VALU
// issue is the binding pipe (~37 us kernel), so halving accum instructions
// should cut ~25%.
// Algorithm (R7): k(i,j) = t_n^{i^2} * t_n^{j^2}, masked t=0 kills OOB taps.
//   Pass V: C_a(y,x) = sum_i img(y+i,x) * t(y+i,x)^(i^2+a), a in {0,1,4,9,16,25}
//   Pass H: out(y,x) = sum_j C_{j^2}(y,x+j) / sum_j W_{j^2}(y,x+j)
// Codegen rules (R1-R6): scalar/constexpr-indexed accumulators, straight-line
// unrolls, no guarded multi-output inner loops (those spilled to VGPR=256).
__global__ __launch_bounds__(320) void gauss_psf_kernel(const float* __restrict__ image,
                                                        const float* __restrict__ psf,
                                                        float* __restrict__ out) {
    __shared__ float4 cp[6 * NSTRIP];   // class planes (ch0,ch1,ch2,w), 28.4 KB
    __shared__ float  tt[SH * SW];      // masked t tile, 4.1 KB

    const int tx  = threadIdx.x;            // 0..63
    const int ty  = threadIdx.y;            // 0..4
    const int tid = ty * 64 + tx;           // 0..319
    const int bx0 = blockIdx.x * TW;
    const int by0 = blockIdx.y * TH;
    const int b   = blockIdx.z;

    const float* pw   = psf + (size_t)b * HH * WW;
    const float* img0 = image + (size_t)b * 3 * HH * WW;
    const float* img1 = img0 + HH * WW;
    const float* img2 = img0 + 2 * HH * WW;

    // ---- Phase 1: masked-t tile (14 x 74 = 1036 values) ----
#pragma unroll
    for (int base = 0; base < SH * SW; base += 320) {
        const int idx = base + tid;
        if (idx < SH * SW) {
            const int row = idx / SW, col = idx - row * SW;
            const int gy = by0 - RR + row, gx = bx0 - RR + col;
            const bool in = ((unsigned)gy < (unsigned)HH) && ((unsigned)gx < (unsigned)WW);
            const int cy = gy < 0 ? 0 : (gy > HH - 1 ? HH - 1 : gy);
            const int cx = gx < 0 ? 0 : (gx > WW - 1 ? WW - 1 : gx);
            const float w = pw[cy * WW + cx];
            const float a = -NLOG2E * __builtin_amdgcn_rcpf(fmaf(2.0f * w, w, EPS_F));
            tt[idx] = in ? __builtin_amdgcn_exp2f(a) : 0.0f;
        }
    }
    __syncthreads();

    // ---- Pass V: 296 strip pixels, one per thread ----
    if (tid < NSTRIP) {
        const int ly = tid / SW;            // 0..3
        const int lx = tid - ly * SW;       // 0..73
        const int gx = bx0 - RR + lx;
        const int gxc = gx < 0 ? 0 : (gx > WW - 1 ? WW - 1 : gx);
        const int gy = by0 + ly;

        // Class-pair accumulators: [p] = classes (2p, 2p+1); channels 0,1,2 + w.
        f2 a0p[3], a1p[3], a2p[3], awp[3];
#pragma unroll
        for (int p = 0; p < 3; ++p) {
            a0p[p] = (f2)0.0f; a1p[p] = (f2)0.0f; a2p[p] = (f2)0.0f; awp[p] = (f2)0.0f;
        }

#pragma unroll
        for (int r = 0; r < KS; ++r) {
            const float t = tt[(ly + r) * SW + lx];            // ds_read, const off
            int ry = gy + r - RR;
            ry = ry < 0 ? 0 : (ry > HH - 1 ? HH - 1 : ry);
            const int ni = ry * WW + gxc;
            const float i0 = img0[ni];
            const float i1 = img1[ni];
            const float i2 = img2[ni];

            // powers t^{1,4,9,16,25} (7 scalar muls)
            const float t2 = t * t, t4 = t2 * t2, t8 = t4 * t4;
            const float t9 = t8 * t, t16 = t8 * t8, t25 = t16 * t9;

            const int ii = (r - RR) * (r - RR);                // constexpr after unroll
            const float u = ii == 0 ? 1.0f : ii == 1 ? t : ii == 4 ? t4
                          : ii == 9 ? t9 : ii == 16 ? t16 : t25;   // t^(i^2)

            const f2 u2  = {u, u};
            const f2 f01 = u2 * (f2){1.0f, t};                 // t^(i^2+{0,1})
            const f2 f23 = u2 * (f2){t4, t9};                  // t^(i^2+{4,9})
            const f2 f45 = u2 * (f2){t16, t25};                // t^(i^2+{16,25})

            const f2 i0v = {i0, i0}, i1v = {i1, i1}, i2v = {i2, i2};
            a0p[0] = fma2(i0v, f01, a0p[0]);
            a0p[1] = fma2(i0v, f23, a0p[1]);
            a0p[2] = fma2(i0v, f45, a0p[2]);
            a1p[0] = fma2(i1v, f01, a1p[0]);
            a1p[1] = fma2(i1v, f23, a1p[1]);
            a1p[2] = fma2(i1v, f45, a1p[2]);
            a2p[0] = fma2(i2v, f01, a2p[0]);
            a2p[1] = fma2(i2v, f23, a2p[1]);
            a2p[2] = fma2(i2v, f45, a2p[2]);
            awp[0] += f01;
            awp[1] += f23;
            awp[2] += f45;
        }

#pragma unroll
        for (int p = 0; p < 3; ++p) {                          // 6 ds_write_b128
            cp[(2 * p) * NSTRIP + tid]     = make_float4(a0p[p].x, a1p[p].x, a2p[p].x, awp[p].x);
            cp[(2 * p + 1) * NSTRIP + tid] = make_float4(a0p[p].y, a1p[p].y, a2p[p].y, awp[p].y);
        }
    }
    __syncthreads();

    // ---- Pass H: 256 output pixels (waves 0-3); wave 4 exits uniformly ----
    if (tid < TW * TH) {
        const int hx = tid & 63, hy = tid >> 6;
        const int hb = hy * SW + hx;        // strip index of (y, x-RR+j) at j=0
        f2 s01 = (f2)0.0f, s2w = (f2)0.0f;
#pragma unroll
        for (int j = 0; j < KS; ++j) {
            const int jj = (j - RR) * (j - RR);                // constexpr
            const int ai = jj == 0 ? 0 : jj == 1 ? 1 : jj == 4 ? 2
                         : jj == 9 ? 3 : jj == 16 ? 4 : 5;
            const float4 v = cp[ai * NSTRIP + hb + j];         // ds_read_b128
            s01 += (f2){v.x, v.y};                             // pk_add
            s2w += (f2){v.z, v.w};
        }

        const float sw = s2w.y;                                // >= 1 (center tap)
        float inv = __builtin_amdgcn_rcpf(sw);
        inv = inv * (2.0f - sw * inv);                         // Newton: ~1e-7 rel
        const int x = bx0 + hx, y = by0 + hy;
        const int oi = y * WW + x;
        float* outb = out + (size_t)b * 3 * HH * WW;
        outb[oi]               = s01.x * inv;
        outb[HH * WW + oi]     = s01.y * inv;
        outb[2 * HH * WW + oi] = s2w.x * inv;
    }
}

extern "C" void kernel_launch(void* const* d_in, const int* in_sizes, int n_in,
                              void* d_out, int out_size, void* d_ws, size_t ws_size,
                              hipStream_t stream) {
    const float* image = (const float*)d_in[0];
    const float* psf   = (const float*)d_in[1];
    float* out = (float*)d_out;

    dim3 block(TW, BY, 1);                 // 320 threads = 5 waves
    dim3 grid(WW / TW, HH / TH, 4);        // 8 x 128 x 4 = 4096 blocks
    gauss_psf_kernel<<<grid, block, 0, stream>>>(image, psf, out);
}